// Round 3
// baseline (2084.531 us; speedup 1.0000x reference)
//
#include <hip/hip_runtime.h>
#include <hip/hip_bf16.h>
#include <math.h>

// ============================================================================
// XCA-style transposed attention, fp32, per-batch (ws = 302 MB)
//
// Per batch b (4 iterations):
//  K1 conv1x1      : qkv_pre = W(576x192) @ x_b          -> buf_pre (151 MB)
//  K2 dw3x3+l2norm : depthwise 3x3 SAME, then L2-normalize q,k rows  -> buf_post
//  K3 qkt_softmax  : per-slice (192) P = softmax(Qn Kn^T * temp)     -> A (reuse buf_pre)
//  K4 pv_gemm      : per-slice O = P @ V                 -> O (reuse buf_pre upper)
//  K5 conv1x1      : out_b = P(192x192) @ O + b
// ============================================================================

#define HW 65536
#define IMW 256

// ---- K1/K5: 1x1 conv as GEMM. tile 64 oc x 256 px, K-step 16, 256 thr, 8x8/thr
__global__ __launch_bounds__(256) void conv1x1(const float* __restrict__ in,
                                               const float* __restrict__ wgt,
                                               const float* __restrict__ bias,
                                               float* __restrict__ out,
                                               int K)
{
    int oc0 = blockIdx.y * 64;
    int p0  = blockIdx.x * 256;

    __shared__ float Ws[16][64];    // [k][oc]
    __shared__ float Xs[16][256];   // [k][px]

    int t  = threadIdx.x;
    int ty = t >> 5;   // 0..7 -> oc octet
    int tx = t & 31;   // 0..31 -> px quads

    float acc[8][8];
    #pragma unroll
    for (int i = 0; i < 8; ++i)
        #pragma unroll
        for (int j = 0; j < 8; ++j) acc[i][j] = 0.f;

    for (int k0 = 0; k0 < K; k0 += 16) {
        {   // stage W tile transposed: 64 oc x 16 k
            int ocr = t >> 2, kc = (t & 3) * 4;
            float4 wv = *(const float4*)&wgt[(size_t)(oc0 + ocr) * K + k0 + kc];
            Ws[kc + 0][ocr] = wv.x; Ws[kc + 1][ocr] = wv.y;
            Ws[kc + 2][ocr] = wv.z; Ws[kc + 3][ocr] = wv.w;
        }
        {   // stage X tile natural: 16 k x 256 px
            int kr = t >> 6, pc = (t & 63) * 4;
            #pragma unroll
            for (int i = 0; i < 4; ++i)
                *(float4*)&Xs[kr + 4 * i][pc] =
                    *(const float4*)&in[(size_t)(k0 + kr + 4 * i) * HW + p0 + pc];
        }
        __syncthreads();
        #pragma unroll
        for (int kk = 0; kk < 16; ++kk) {
            float a[8], bb[8];
            *(float4*)&a[0]  = *(const float4*)&Ws[kk][ty * 8];
            *(float4*)&a[4]  = *(const float4*)&Ws[kk][ty * 8 + 4];
            *(float4*)&bb[0] = *(const float4*)&Xs[kk][tx * 4];
            *(float4*)&bb[4] = *(const float4*)&Xs[kk][128 + tx * 4];
            #pragma unroll
            for (int i = 0; i < 8; ++i)
                #pragma unroll
                for (int j = 0; j < 8; ++j) acc[i][j] += a[i] * bb[j];
        }
        __syncthreads();
    }
    #pragma unroll
    for (int i = 0; i < 8; ++i) {
        int oc = oc0 + ty * 8 + i;
        float bv = bias[oc];
        float* orow = out + (size_t)oc * HW + p0;
        *(float4*)&orow[tx * 4] =
            make_float4(acc[i][0] + bv, acc[i][1] + bv, acc[i][2] + bv, acc[i][3] + bv);
        *(float4*)&orow[128 + tx * 4] =
            make_float4(acc[i][4] + bv, acc[i][5] + bv, acc[i][6] + bv, acc[i][7] + bv);
    }
}

// ---- K2: depthwise 3x3 SAME + fused row L2-norm for q,k channels.
// one wave = one full image row (256 px); block = 4 rows. per-batch base ptrs.
__global__ __launch_bounds__(256) void dw3x3_l2norm(const float* __restrict__ in,
                                                    const float* __restrict__ w,
                                                    const float* __restrict__ bias,
                                                    float* __restrict__ out)
{
    int t = threadIdx.x;
    long gr = (long)blockIdx.x * 4 + (t >> 6);   // row index over 576*256
    int lane = t & 63;
    int h  = (int)(gr & 255);
    int ch = (int)(gr >> 8);                     // 0..575
    const float* img  = in  + (size_t)ch * HW;
    float*       outp = out + (size_t)ch * HW + (size_t)h * IMW;
    int px = lane * 4;

    const float* wch = w + ch * 9;
    float bv = bias[ch];
    float acc[4] = {bv, bv, bv, bv};
    #pragma unroll
    for (int dy = 0; dy < 3; ++dy) {
        int hh = h + dy - 1;
        if ((unsigned)hh > 255u) continue;
        const float* rowp = img + (size_t)hh * IMW;
        float v[6];
        float4 cv = *(const float4*)&rowp[px];
        v[1] = cv.x; v[2] = cv.y; v[3] = cv.z; v[4] = cv.w;
        v[0] = (px > 0)   ? rowp[px - 1] : 0.f;
        v[5] = (px < 252) ? rowp[px + 4] : 0.f;
        float w0 = wch[dy * 3], w1 = wch[dy * 3 + 1], w2 = wch[dy * 3 + 2];
        #pragma unroll
        for (int j = 0; j < 4; ++j)
            acc[j] += v[j] * w0 + v[j + 1] * w1 + v[j + 2] * w2;
    }
    if (ch < 384) {   // q or k channel: L2-normalize along W
        float ss = acc[0]*acc[0] + acc[1]*acc[1] + acc[2]*acc[2] + acc[3]*acc[3];
        #pragma unroll
        for (int m = 1; m < 64; m <<= 1) ss += __shfl_xor(ss, m, 64);
        float inv = 1.0f / fmaxf(sqrtf(ss), 1e-12f);
        acc[0] *= inv; acc[1] *= inv; acc[2] *= inv; acc[3] *= inv;
    }
    *(float4*)&outp[px] = make_float4(acc[0], acc[1], acc[2], acc[3]);
}

// ---- K3: per-slice P = softmax(Qn Kn^T * temp), tile 64x x 256y (full rows)
// grid (4 x-tiles, 192 slices). 256 thr: ty=t>>4 (4 rows each), tx=t&15 (16 y each)
__global__ __launch_bounds__(256) void qkt_softmax(const float* __restrict__ qkv,
                                                   float* __restrict__ A,
                                                   const float* __restrict__ temp)
{
    int r = blockIdx.y;            // channel 0..191
    int n = r >> 5;                // head
    const float* qp = qkv + (size_t)r * HW;
    const float* kp = qkv + (size_t)(192 + r) * HW;
    float* Ap = A + (size_t)r * HW;
    int x0 = blockIdx.x * 64;

    __shared__ float Qs[16][64];    // [w][x]
    __shared__ float Ks[16][256];   // [w][y]
    int t = threadIdx.x;
    int ty = t >> 4, tx = t & 15;
    float acc[4][16];
    #pragma unroll
    for (int i = 0; i < 4; ++i)
        #pragma unroll
        for (int j = 0; j < 16; ++j) acc[i][j] = 0.f;

    for (int w0 = 0; w0 < 256; w0 += 16) {
        {   // Q tile 64x x 16w, transposed store
            int xr = t >> 2, wc = (t & 3) * 4;
            float4 qv = *(const float4*)&qp[(size_t)(x0 + xr) * IMW + w0 + wc];
            Qs[wc + 0][xr] = qv.x; Qs[wc + 1][xr] = qv.y;
            Qs[wc + 2][xr] = qv.z; Qs[wc + 3][xr] = qv.w;
        }
        #pragma unroll
        for (int half = 0; half < 4; ++half) {   // K tile 256y x 16w
            int idx = t + half * 256;
            int yr = idx >> 2, wc = (idx & 3) * 4;
            float4 kv = *(const float4*)&kp[(size_t)yr * IMW + w0 + wc];
            Ks[wc + 0][yr] = kv.x; Ks[wc + 1][yr] = kv.y;
            Ks[wc + 2][yr] = kv.z; Ks[wc + 3][yr] = kv.w;
        }
        __syncthreads();
        #pragma unroll
        for (int kk = 0; kk < 16; ++kk) {
            float a[4], bb[16];
            *(float4*)&a[0]   = *(const float4*)&Qs[kk][ty * 4];
            *(float4*)&bb[0]  = *(const float4*)&Ks[kk][tx * 4];
            *(float4*)&bb[4]  = *(const float4*)&Ks[kk][64 + tx * 4];
            *(float4*)&bb[8]  = *(const float4*)&Ks[kk][128 + tx * 4];
            *(float4*)&bb[12] = *(const float4*)&Ks[kk][192 + tx * 4];
            #pragma unroll
            for (int i = 0; i < 4; ++i)
                #pragma unroll
                for (int j = 0; j < 16; ++j) acc[i][j] += a[i] * bb[j];
        }
        __syncthreads();
    }

    float tv = temp[n];
    // per-row softmax: row owned by the 16 tx-lanes of this ty-group (same wave)
    #pragma unroll
    for (int i = 0; i < 4; ++i) {
        float m = -1e30f;
        #pragma unroll
        for (int j = 0; j < 16; ++j) { acc[i][j] *= tv; m = fmaxf(m, acc[i][j]); }
        #pragma unroll
        for (int s = 1; s < 16; s <<= 1) m = fmaxf(m, __shfl_xor(m, s, 64));
        float sum = 0.f;
        #pragma unroll
        for (int j = 0; j < 16; ++j) { acc[i][j] = expf(acc[i][j] - m); sum += acc[i][j]; }
        #pragma unroll
        for (int s = 1; s < 16; s <<= 1) sum += __shfl_xor(sum, s, 64);
        float inv = 1.0f / sum;
        float* orow = Ap + (size_t)(x0 + ty * 4 + i) * IMW;
        #pragma unroll
        for (int seg = 0; seg < 4; ++seg)
            *(float4*)&orow[seg * 64 + tx * 4] =
                make_float4(acc[i][seg*4+0] * inv, acc[i][seg*4+1] * inv,
                            acc[i][seg*4+2] * inv, acc[i][seg*4+3] * inv);
    }
}

// ---- K4: per-slice O = P @ V.  tile 64x x 128w, K-step 16 (y). grid (2,4,192)
__global__ __launch_bounds__(256) void pv_gemm(const float* __restrict__ A,
                                               const float* __restrict__ qkv,
                                               float* __restrict__ O)
{
    int r = blockIdx.z;
    const float* Ap = A + (size_t)r * HW;
    const float* vp = qkv + (size_t)(384 + r) * HW;
    float* Op = O + (size_t)r * HW;
    int x0 = blockIdx.y * 64, w0 = blockIdx.x * 128;

    __shared__ float Ps[16][64];    // [y][x]
    __shared__ float Vs[16][128];   // [y][w]
    int t = threadIdx.x;
    int ty = t >> 4, tx = t & 15;
    float acc[4][8];
    #pragma unroll
    for (int i = 0; i < 4; ++i)
        #pragma unroll
        for (int j = 0; j < 8; ++j) acc[i][j] = 0.f;

    for (int y0 = 0; y0 < 256; y0 += 16) {
        {   int xr = t >> 2, yc = (t & 3) * 4;
            float4 pv4 = *(const float4*)&Ap[(size_t)(x0 + xr) * IMW + y0 + yc];
            Ps[yc + 0][xr] = pv4.x; Ps[yc + 1][xr] = pv4.y;
            Ps[yc + 2][xr] = pv4.z; Ps[yc + 3][xr] = pv4.w;
        }
        #pragma unroll
        for (int half = 0; half < 2; ++half) {
            int idx = t + half * 256;
            int yr = idx >> 5, wc2 = (idx & 31) * 4;
            *(float4*)&Vs[yr][wc2] =
                *(const float4*)&vp[(size_t)(y0 + yr) * IMW + w0 + wc2];
        }
        __syncthreads();
        #pragma unroll
        for (int kk = 0; kk < 16; ++kk) {
            float a[4], bb[8];
            *(float4*)&a[0]  = *(const float4*)&Ps[kk][ty * 4];
            *(float4*)&bb[0] = *(const float4*)&Vs[kk][tx * 4];
            *(float4*)&bb[4] = *(const float4*)&Vs[kk][64 + tx * 4];
            #pragma unroll
            for (int i = 0; i < 4; ++i)
                #pragma unroll
                for (int j = 0; j < 8; ++j) acc[i][j] += a[i] * bb[j];
        }
        __syncthreads();
    }
    #pragma unroll
    for (int i = 0; i < 4; ++i) {
        float* orow = Op + (size_t)(x0 + ty * 4 + i) * IMW + w0;
        *(float4*)&orow[tx * 4] = make_float4(acc[i][0], acc[i][1], acc[i][2], acc[i][3]);
        *(float4*)&orow[64 + tx * 4] = make_float4(acc[i][4], acc[i][5], acc[i][6], acc[i][7]);
    }
}

extern "C" void kernel_launch(void* const* d_in, const int* in_sizes, int n_in,
                              void* d_out, int out_size, void* d_ws, size_t ws_size,
                              hipStream_t stream)
{
    const float* x      = (const float*)d_in[0];
    const float* qkv_w  = (const float*)d_in[1];
    const float* qkv_b  = (const float*)d_in[2];
    const float* dw_w   = (const float*)d_in[3];
    const float* dw_b   = (const float*)d_in[4];
    const float* proj_w = (const float*)d_in[5];
    const float* proj_b = (const float*)d_in[6];
    const float* temp   = (const float*)d_in[7];
    float* out = (float*)d_out;

    const size_t PB = (size_t)576 * HW;               // 37,748,736 floats per batch
    if (ws_size < 2 * PB * sizeof(float)) return;     // need 302 MB scratch

    float* buf_pre  = (float*)d_ws;       // conv1x1 out; later A (lower) + O (upper)
    float* buf_post = buf_pre + PB;       // dw+norm out (q|k|v)
    float* Abuf = buf_pre;                            // 192*HW floats
    float* Obuf = buf_pre + (size_t)192 * HW;         // 192*HW floats

    for (int b = 0; b < 4; ++b) {
        const float* xb  = x   + (size_t)b * 192 * HW;
        float*       ob  = out + (size_t)b * 192 * HW;
        // K1: qkv 1x1 conv (576 oc, K=192)
        conv1x1<<<dim3(256, 9), 256, 0, stream>>>(xb, qkv_w, qkv_b, buf_pre, 192);
        // K2: depthwise 3x3 + L2 norm of q,k rows
        dw3x3_l2norm<<<dim3(36864), 256, 0, stream>>>(buf_pre, dw_w, dw_b, buf_post);
        // K3: P = softmax(Qn Kn^T * temp)
        qkt_softmax<<<dim3(4, 192), 256, 0, stream>>>(buf_post, Abuf, temp);
        // K4: O = P @ V
        pv_gemm<<<dim3(2, 4, 192), 256, 0, stream>>>(Abuf, buf_post, Obuf);
        // K5: proj 1x1 conv (192 oc, K=192)
        conv1x1<<<dim3(256, 3), 256, 0, stream>>>(Obuf, proj_w, proj_b, ob, 192);
    }
}

// Round 4
// 1093.353 us; speedup vs baseline: 1.9065x; 1.9065x over previous
//
#include <hip/hip_runtime.h>
#include <hip/hip_bf16.h>
#include <math.h>

// ============================================================================
// XCA transposed attention, bf16-MFMA pipeline (round 3)
// Per batch: cvt+transpose(x)->Xt | qkv=W@Xt (MFMA) | dw3x3+l2norm (bf16) |
//            V->Vt | P=softmax(QK^T*t) (MFMA+fused softmax) | O=P@Vt (MFMA) |
//            O->Ot | out=Wp@Ot+b (MFMA, fp32 out)
// ============================================================================

#define HW 65536
#define IMW 256

typedef short bf16x8 __attribute__((ext_vector_type(8)));
typedef float f32x4  __attribute__((ext_vector_type(4)));

__device__ __forceinline__ float bf2f(ushort u) {
    return __uint_as_float((uint)u << 16);
}
__device__ __forceinline__ ushort f2bf(float f) {
    uint i = __float_as_uint(f);
    return (ushort)((i + 0x7FFFu + ((i >> 16) & 1u)) >> 16);
}

// ---- flat fp32 -> bf16 (weights)
__global__ __launch_bounds__(256) void cvt_f32_bf16(const float* __restrict__ s,
                                                    ushort* __restrict__ d, int n)
{
    int i = blockIdx.x * 256 + threadIdx.x;
    if (i < n) d[i] = f2bf(s[i]);
}

// ---- fp32 [R][C] -> bf16 [C][R] transpose+convert, 64x64 tiles
__global__ __launch_bounds__(256) void cvt_transpose_f32(const float* __restrict__ src,
                                                         ushort* __restrict__ dst,
                                                         int R, int C)
{
    __shared__ ushort Ls[64][72];
    int t = threadIdx.x;
    int c0 = blockIdx.x * 64, r0 = blockIdx.y * 64;
    {
        int r = t >> 2, cs = t & 3;
        const float* gp = src + (size_t)(r0 + r) * C + c0 + cs * 16;
        ushort tmp[16];
        #pragma unroll
        for (int q = 0; q < 4; ++q) {
            float4 v = *(const float4*)(gp + q * 4);
            tmp[q*4+0] = f2bf(v.x); tmp[q*4+1] = f2bf(v.y);
            tmp[q*4+2] = f2bf(v.z); tmp[q*4+3] = f2bf(v.w);
        }
        *(uint4*)&Ls[r][cs * 16]     = *(uint4*)&tmp[0];
        *(uint4*)&Ls[r][cs * 16 + 8] = *(uint4*)&tmp[8];
    }
    __syncthreads();
    {
        int cc = t & 63, seg = t >> 6;
        ushort tmp[16];
        #pragma unroll
        for (int j = 0; j < 16; ++j) tmp[j] = Ls[seg * 16 + j][cc];
        ushort* op = dst + (size_t)(c0 + cc) * R + r0 + seg * 16;
        *(uint4*)(op)     = *(uint4*)&tmp[0];
        *(uint4*)(op + 8) = *(uint4*)&tmp[8];
    }
}

// ---- bf16 [R][C] -> bf16 [C][R] transpose, 64x64 tiles, batched slices
__global__ __launch_bounds__(256) void transpose_bf16(const ushort* __restrict__ src,
                                                      ushort* __restrict__ dst,
                                                      int R, int C,
                                                      long ssS, long ssD)
{
    __shared__ ushort Ls[64][72];
    int t = threadIdx.x;
    long z = blockIdx.z;
    src += z * ssS; dst += z * ssD;
    int c0 = blockIdx.x * 64, r0 = blockIdx.y * 64;
    {
        int r = t >> 2, cs = t & 3;
        const ushort* gp = src + (size_t)(r0 + r) * C + c0 + cs * 16;
        *(uint4*)&Ls[r][cs * 16]     = *(const uint4*)(gp);
        *(uint4*)&Ls[r][cs * 16 + 8] = *(const uint4*)(gp + 8);
    }
    __syncthreads();
    {
        int cc = t & 63, seg = t >> 6;
        ushort tmp[16];
        #pragma unroll
        for (int j = 0; j < 16; ++j) tmp[j] = Ls[seg * 16 + j][cc];
        ushort* op = dst + (size_t)(c0 + cc) * R + r0 + seg * 16;
        *(uint4*)(op)     = *(uint4*)&tmp[0];
        *(uint4*)(op + 8) = *(uint4*)&tmp[8];
    }
}

// ---- generic MFMA GEMM: D[m][n] = sum_k A[m][k]*B[n][k] (+bias[m])
// A: M x K row-major bf16 (lda), B: N x K row-major bf16 (ldb, i.e. B^T layout)
// tile: 64M x 256N per block, 4 waves each 16M x 256N, K-step 32
__global__ __launch_bounds__(256) void gemm_mfma(const ushort* __restrict__ A, int lda, long sliceA,
                                                 const ushort* __restrict__ B, int ldb, long sliceB,
                                                 void* __restrict__ Dp, int ldd, long sliceD,
                                                 const float* __restrict__ bias,
                                                 int K, int outF32)
{
    __shared__ ushort Ws[64][40];
    __shared__ ushort Xs[256][40];
    int t = threadIdx.x, wv = t >> 6, lane = t & 63;
    long z = blockIdx.z;
    A += z * sliceA; B += z * sliceB;
    int m0 = blockIdx.y * 64, n0 = blockIdx.x * 256;

    f32x4 acc[16];
    #pragma unroll
    for (int i = 0; i < 16; ++i) acc[i] = (f32x4){0.f, 0.f, 0.f, 0.f};

    for (int k0 = 0; k0 < K; k0 += 32) {
        {   // stage A tile 64 x 32
            int r = t >> 2, s = t & 3;
            *(uint4*)&Ws[r][s * 8] =
                *(const uint4*)(A + (size_t)(m0 + r) * lda + k0 + s * 8);
        }
        {   // stage B tile 256 x 32
            const ushort* bp = B + (size_t)(n0 + t) * ldb + k0;
            #pragma unroll
            for (int s = 0; s < 4; ++s)
                *(uint4*)&Xs[t][s * 8] = *(const uint4*)(bp + s * 8);
        }
        __syncthreads();
        bf16x8 a = *(const bf16x8*)&Ws[wv * 16 + (lane & 15)][(lane >> 4) * 8];
        #pragma unroll
        for (int nt = 0; nt < 16; ++nt) {
            bf16x8 b = *(const bf16x8*)&Xs[nt * 16 + (lane & 15)][(lane >> 4) * 8];
            acc[nt] = __builtin_amdgcn_mfma_f32_16x16x32_bf16(a, b, acc[nt], 0, 0, 0);
        }
        __syncthreads();
    }

    int mrow = m0 + wv * 16 + (lane >> 4) * 4;
    int ncol = n0 + (lane & 15);
    if (outF32) {
        float* D = (float*)Dp + z * sliceD;
        #pragma unroll
        for (int r_ = 0; r_ < 4; ++r_) {
            float bv = bias ? bias[mrow + r_] : 0.f;
            #pragma unroll
            for (int nt = 0; nt < 16; ++nt)
                D[(size_t)(mrow + r_) * ldd + ncol + nt * 16] = acc[nt][r_] + bv;
        }
    } else {
        ushort* D = (ushort*)Dp + z * sliceD;
        #pragma unroll
        for (int r_ = 0; r_ < 4; ++r_) {
            float bv = bias ? bias[mrow + r_] : 0.f;
            #pragma unroll
            for (int nt = 0; nt < 16; ++nt)
                D[(size_t)(mrow + r_) * ldd + ncol + nt * 16] = f2bf(acc[nt][r_] + bv);
        }
    }
}

// ---- QK^T * temp -> row softmax -> P (bf16). Per slice z (192), M-tile 64.
// wave owns 16 rows x full 256 cols -> softmax fully in-register + shfl
__global__ __launch_bounds__(256) void qkt_softmax_mfma(const ushort* __restrict__ qkv,
                                                        const float* __restrict__ temp,
                                                        ushort* __restrict__ P)
{
    __shared__ ushort Ws[64][40];
    __shared__ ushort Xs[256][40];
    int t = threadIdx.x, wv = t >> 6, lane = t & 63;
    int z = blockIdx.y;                 // channel slice 0..191
    const ushort* Aq = qkv + (size_t)z * HW;          // Q slice [256][256]
    const ushort* Bk = qkv + (size_t)(192 + z) * HW;  // K slice [256][256]
    int m0 = blockIdx.x * 64;

    f32x4 acc[16];
    #pragma unroll
    for (int i = 0; i < 16; ++i) acc[i] = (f32x4){0.f, 0.f, 0.f, 0.f};

    for (int k0 = 0; k0 < 256; k0 += 32) {
        {
            int r = t >> 2, s = t & 3;
            *(uint4*)&Ws[r][s * 8] =
                *(const uint4*)(Aq + (size_t)(m0 + r) * IMW + k0 + s * 8);
        }
        {
            const ushort* bp = Bk + (size_t)t * IMW + k0;
            #pragma unroll
            for (int s = 0; s < 4; ++s)
                *(uint4*)&Xs[t][s * 8] = *(const uint4*)(bp + s * 8);
        }
        __syncthreads();
        bf16x8 a = *(const bf16x8*)&Ws[wv * 16 + (lane & 15)][(lane >> 4) * 8];
        #pragma unroll
        for (int nt = 0; nt < 16; ++nt) {
            bf16x8 b = *(const bf16x8*)&Xs[nt * 16 + (lane & 15)][(lane >> 4) * 8];
            acc[nt] = __builtin_amdgcn_mfma_f32_16x16x32_bf16(a, b, acc[nt], 0, 0, 0);
        }
        __syncthreads();
    }

    float tv = temp[z >> 5];
    #pragma unroll
    for (int r_ = 0; r_ < 4; ++r_) {
        float v[16];
        float mx = -3.4e38f;
        #pragma unroll
        for (int nt = 0; nt < 16; ++nt) { v[nt] = acc[nt][r_] * tv; mx = fmaxf(mx, v[nt]); }
        #pragma unroll
        for (int s = 1; s < 16; s <<= 1) mx = fmaxf(mx, __shfl_xor(mx, s, 64));
        float sum = 0.f;
        #pragma unroll
        for (int nt = 0; nt < 16; ++nt) { v[nt] = __expf(v[nt] - mx); sum += v[nt]; }
        #pragma unroll
        for (int s = 1; s < 16; s <<= 1) sum += __shfl_xor(sum, s, 64);
        float inv = 1.f / sum;
        int m = m0 + wv * 16 + (lane >> 4) * 4 + r_;
        ushort* prow = P + (size_t)z * HW + (size_t)m * IMW + (lane & 15);
        #pragma unroll
        for (int nt = 0; nt < 16; ++nt) prow[nt * 16] = f2bf(v[nt] * inv);
    }
}

// ---- depthwise 3x3 SAME + fused L2 row-norm (q,k), bf16 in/out, fp32 math
__global__ __launch_bounds__(256) void dw3x3_l2norm(const ushort* __restrict__ in,
                                                    const float* __restrict__ w,
                                                    const float* __restrict__ bias,
                                                    ushort* __restrict__ out)
{
    int t = threadIdx.x;
    long gr = (long)blockIdx.x * 4 + (t >> 6);   // row over 576*256
    int lane = t & 63;
    int h  = (int)(gr & 255);
    int ch = (int)(gr >> 8);
    const ushort* img  = in  + (size_t)ch * HW;
    ushort*       outp = out + (size_t)ch * HW + (size_t)h * IMW;
    int px = lane * 4;

    const float* wch = w + ch * 9;
    float bv = bias[ch];
    float acc[4] = {bv, bv, bv, bv};
    #pragma unroll
    for (int dy = 0; dy < 3; ++dy) {
        int hh = h + dy - 1;
        if ((unsigned)hh > 255u) continue;
        const ushort* rowp = img + (size_t)hh * IMW;
        float v[6];
        ushort4 cv = *(const ushort4*)&rowp[px];
        v[1] = bf2f(cv.x); v[2] = bf2f(cv.y); v[3] = bf2f(cv.z); v[4] = bf2f(cv.w);
        v[0] = (px > 0)   ? bf2f(rowp[px - 1]) : 0.f;
        v[5] = (px < 252) ? bf2f(rowp[px + 4]) : 0.f;
        float w0 = wch[dy * 3], w1 = wch[dy * 3 + 1], w2 = wch[dy * 3 + 2];
        #pragma unroll
        for (int j = 0; j < 4; ++j)
            acc[j] += v[j] * w0 + v[j + 1] * w1 + v[j + 2] * w2;
    }
    if (ch < 384) {
        float ss = acc[0]*acc[0] + acc[1]*acc[1] + acc[2]*acc[2] + acc[3]*acc[3];
        #pragma unroll
        for (int m = 1; m < 64; m <<= 1) ss += __shfl_xor(ss, m, 64);
        float inv = 1.0f / fmaxf(sqrtf(ss), 1e-12f);
        acc[0] *= inv; acc[1] *= inv; acc[2] *= inv; acc[3] *= inv;
    }
    ushort4 o;
    o.x = f2bf(acc[0]); o.y = f2bf(acc[1]); o.z = f2bf(acc[2]); o.w = f2bf(acc[3]);
    *(ushort4*)&outp[px] = o;
}

extern "C" void kernel_launch(void* const* d_in, const int* in_sizes, int n_in,
                              void* d_out, int out_size, void* d_ws, size_t ws_size,
                              hipStream_t stream)
{
    const float* x      = (const float*)d_in[0];
    const float* qkv_w  = (const float*)d_in[1];
    const float* qkv_b  = (const float*)d_in[2];
    const float* dw_w   = (const float*)d_in[3];
    const float* dw_b   = (const float*)d_in[4];
    const float* proj_w = (const float*)d_in[5];
    const float* proj_b = (const float*)d_in[6];
    const float* temp   = (const float*)d_in[7];
    float* out = (float*)d_out;

    // ws layout (ushort elements)
    const size_t off_wq   = 0;                       // 576*192
    const size_t off_wp   = 110592;                  // 192*192
    const size_t off_pre  = 262144;                  // 576*HW  (qkv pre-dw)
    const size_t off_post = off_pre + (size_t)576 * HW;   // 576*HW (q|k|v)
    const size_t off_xt   = off_post + (size_t)576 * HW;  // 192*HW (Xt, later Vt)
    const size_t off_ot   = off_xt + (size_t)192 * HW;    // 192*HW (Ot)
    const size_t total_us = off_ot + (size_t)192 * HW;    // 100,925,440 ushorts
    if (ws_size < total_us * sizeof(ushort)) return;      // ~202 MB

    ushort* wsb  = (ushort*)d_ws;
    ushort* wq   = wsb + off_wq;
    ushort* wp   = wsb + off_wp;
    ushort* pre  = wsb + off_pre;
    ushort* post = wsb + off_post;
    ushort* xt   = wsb + off_xt;      // Xt then Vt
    ushort* ot   = wsb + off_ot;
    ushort* Pbuf = pre;                               // reuse (192*HW)
    ushort* Obuf = pre + (size_t)192 * HW;            // reuse (192*HW)

    // weights -> bf16 (once)
    cvt_f32_bf16<<<dim3(432), 256, 0, stream>>>(qkv_w, wq, 110592);
    cvt_f32_bf16<<<dim3(144), 256, 0, stream>>>(proj_w, wp, 36864);

    for (int b = 0; b < 4; ++b) {
        const float* xb = x   + (size_t)b * 192 * HW;
        float*       ob = out + (size_t)b * 192 * HW;

        // x_b [192][65536] fp32 -> Xt [65536][192] bf16
        cvt_transpose_f32<<<dim3(1024, 3), 256, 0, stream>>>(xb, xt, 192, HW);
        // qkv = Wq @ x : D[576][65536] bf16
        gemm_mfma<<<dim3(256, 9, 1), 256, 0, stream>>>(wq, 192, 0, xt, 192, 0,
                                                       pre, HW, 0, qkv_b, 192, 0);
        // depthwise 3x3 + l2norm(q,k)
        dw3x3_l2norm<<<dim3(36864), 256, 0, stream>>>(pre, dw_w, dw_b, post);
        // V [192 slices][256][256] -> Vt (into xt region)
        transpose_bf16<<<dim3(4, 4, 192), 256, 0, stream>>>(post + (size_t)384 * HW, xt,
                                                            IMW, IMW, (long)HW, (long)HW);
        // P = softmax(Q K^T * temp)
        qkt_softmax_mfma<<<dim3(4, 192), 256, 0, stream>>>(post, temp, Pbuf);
        // O = P @ Vt : per-slice 256x256x256
        gemm_mfma<<<dim3(1, 4, 192), 256, 0, stream>>>(Pbuf, IMW, (long)HW,
                                                       xt, IMW, (long)HW,
                                                       Obuf, IMW, (long)HW,
                                                       nullptr, 256, 0);
        // O [192][65536] -> Ot [65536][192]
        transpose_bf16<<<dim3(1024, 3, 1), 256, 0, stream>>>(Obuf, ot, 192, HW, 0, 0);
        // out = Wp @ O + b : fp32 out
        gemm_mfma<<<dim3(256, 3, 1), 256, 0, stream>>>(wp, 192, 0, ot, 192, 0,
                                                       ob, HW, 0, proj_b, 192, 1);
    }
}

// Round 5
// 1087.593 us; speedup vs baseline: 1.9166x; 1.0053x over previous
//
#include <hip/hip_runtime.h>
#include <hip/hip_bf16.h>
#include <math.h>

// ============================================================================
// XCA transposed attention, bf16-MFMA, round 4: fused attention + batched grids
// Launches (9): cvt(wq), cvt(wp), cvtT(x->Xt), gemm(qkv), dw3x3+l2norm,
//               transpose(V->Vt), fused attn (QK^T*t -> softmax -> P@Vt),
//               transpose(O->Ot), gemm(proj, fp32 out)
// ============================================================================

#define HW 65536
#define IMW 256

typedef short bf16x8 __attribute__((ext_vector_type(8)));
typedef float f32x4  __attribute__((ext_vector_type(4)));

__device__ __forceinline__ float bf2f(ushort u) {
    return __uint_as_float((uint)u << 16);
}
__device__ __forceinline__ ushort f2bf(float f) {
    uint i = __float_as_uint(f);
    return (ushort)((i + 0x7FFFu + ((i >> 16) & 1u)) >> 16);
}

// ---- flat fp32 -> bf16 (weights)
__global__ __launch_bounds__(256) void cvt_f32_bf16(const float* __restrict__ s,
                                                    ushort* __restrict__ d, int n)
{
    int i = blockIdx.x * 256 + threadIdx.x;
    if (i < n) d[i] = f2bf(s[i]);
}

// ---- fp32 [R][C] -> bf16 [C][R] transpose+convert, 64x64 tiles, z-sliced
__global__ __launch_bounds__(256) void cvt_transpose_f32(const float* __restrict__ src,
                                                         ushort* __restrict__ dst,
                                                         int R, int C,
                                                         long ssS, long ssD)
{
    __shared__ ushort Ls[64][72];
    int t = threadIdx.x;
    long z = blockIdx.z;
    src += z * ssS; dst += z * ssD;
    int c0 = blockIdx.x * 64, r0 = blockIdx.y * 64;
    {
        int r = t >> 2, cs = t & 3;
        const float* gp = src + (size_t)(r0 + r) * C + c0 + cs * 16;
        ushort tmp[16];
        #pragma unroll
        for (int q = 0; q < 4; ++q) {
            float4 v = *(const float4*)(gp + q * 4);
            tmp[q*4+0] = f2bf(v.x); tmp[q*4+1] = f2bf(v.y);
            tmp[q*4+2] = f2bf(v.z); tmp[q*4+3] = f2bf(v.w);
        }
        *(uint4*)&Ls[r][cs * 16]     = *(uint4*)&tmp[0];
        *(uint4*)&Ls[r][cs * 16 + 8] = *(uint4*)&tmp[8];
    }
    __syncthreads();
    {
        int cc = t & 63, seg = t >> 6;
        ushort tmp[16];
        #pragma unroll
        for (int j = 0; j < 16; ++j) tmp[j] = Ls[seg * 16 + j][cc];
        ushort* op = dst + (size_t)(c0 + cc) * R + r0 + seg * 16;
        *(uint4*)(op)     = *(uint4*)&tmp[0];
        *(uint4*)(op + 8) = *(uint4*)&tmp[8];
    }
}

// ---- bf16 [R][C] -> bf16 [C][R] transpose, 64x64 tiles, z-sliced (linear strides)
__global__ __launch_bounds__(256) void transpose_bf16(const ushort* __restrict__ src,
                                                      ushort* __restrict__ dst,
                                                      int R, int C,
                                                      long ssS, long ssD)
{
    __shared__ ushort Ls[64][72];
    int t = threadIdx.x;
    long z = blockIdx.z;
    src += z * ssS; dst += z * ssD;
    int c0 = blockIdx.x * 64, r0 = blockIdx.y * 64;
    {
        int r = t >> 2, cs = t & 3;
        const ushort* gp = src + (size_t)(r0 + r) * C + c0 + cs * 16;
        *(uint4*)&Ls[r][cs * 16]     = *(const uint4*)(gp);
        *(uint4*)&Ls[r][cs * 16 + 8] = *(const uint4*)(gp + 8);
    }
    __syncthreads();
    {
        int cc = t & 63, seg = t >> 6;
        ushort tmp[16];
        #pragma unroll
        for (int j = 0; j < 16; ++j) tmp[j] = Ls[seg * 16 + j][cc];
        ushort* op = dst + (size_t)(c0 + cc) * R + r0 + seg * 16;
        *(uint4*)(op)     = *(uint4*)&tmp[0];
        *(uint4*)(op + 8) = *(uint4*)&tmp[8];
    }
}

// ---- V [b][384+r][256][256] -> Vt [s=b*192+r][256][256]^T (s-indexed slices)
__global__ __launch_bounds__(256) void transpose_v(const ushort* __restrict__ post,
                                                   ushort* __restrict__ vt)
{
    __shared__ ushort Ls[64][72];
    int t = threadIdx.x;
    int s = blockIdx.z;
    int b = s / 192, r = s - b * 192;
    const ushort* src = post + ((size_t)b * 576 + 384 + r) * HW;
    ushort*       dst = vt + (size_t)s * HW;
    int c0 = blockIdx.x * 64, r0 = blockIdx.y * 64;
    {
        int rr = t >> 2, cs = t & 3;
        const ushort* gp = src + (size_t)(r0 + rr) * IMW + c0 + cs * 16;
        *(uint4*)&Ls[rr][cs * 16]     = *(const uint4*)(gp);
        *(uint4*)&Ls[rr][cs * 16 + 8] = *(const uint4*)(gp + 8);
    }
    __syncthreads();
    {
        int cc = t & 63, seg = t >> 6;
        ushort tmp[16];
        #pragma unroll
        for (int j = 0; j < 16; ++j) tmp[j] = Ls[seg * 16 + j][cc];
        ushort* op = dst + (size_t)(c0 + cc) * IMW + r0 + seg * 16;
        *(uint4*)(op)     = *(uint4*)&tmp[0];
        *(uint4*)(op + 8) = *(uint4*)&tmp[8];
    }
}

// ---- generic MFMA GEMM: D[m][n] = sum_k A[m][k]*B[n][k] (+bias[m])
// blockIdx.x = m-tile (fastest -> co-resident blocks share B-tile via L2)
__global__ __launch_bounds__(256) void gemm_mfma(const ushort* __restrict__ A, int lda, long sliceA,
                                                 const ushort* __restrict__ B, int ldb, long sliceB,
                                                 void* __restrict__ Dp, int ldd, long sliceD,
                                                 const float* __restrict__ bias,
                                                 int K, int outF32)
{
    __shared__ ushort Ws[64][40];
    __shared__ ushort Xs[256][40];
    int t = threadIdx.x, wv = t >> 6, lane = t & 63;
    long z = blockIdx.z;
    A += z * sliceA; B += z * sliceB;
    int m0 = blockIdx.x * 64, n0 = blockIdx.y * 256;

    f32x4 acc[16];
    #pragma unroll
    for (int i = 0; i < 16; ++i) acc[i] = (f32x4){0.f, 0.f, 0.f, 0.f};

    for (int k0 = 0; k0 < K; k0 += 32) {
        {   int r = t >> 2, s = t & 3;
            *(uint4*)&Ws[r][s * 8] =
                *(const uint4*)(A + (size_t)(m0 + r) * lda + k0 + s * 8);
        }
        {   const ushort* bp = B + (size_t)(n0 + t) * ldb + k0;
            #pragma unroll
            for (int s = 0; s < 4; ++s)
                *(uint4*)&Xs[t][s * 8] = *(const uint4*)(bp + s * 8);
        }
        __syncthreads();
        bf16x8 a = *(const bf16x8*)&Ws[wv * 16 + (lane & 15)][(lane >> 4) * 8];
        #pragma unroll
        for (int nt = 0; nt < 16; ++nt) {
            bf16x8 b = *(const bf16x8*)&Xs[nt * 16 + (lane & 15)][(lane >> 4) * 8];
            acc[nt] = __builtin_amdgcn_mfma_f32_16x16x32_bf16(a, b, acc[nt], 0, 0, 0);
        }
        __syncthreads();
    }

    int mrow = m0 + wv * 16 + (lane >> 4) * 4;
    int ncol = n0 + (lane & 15);
    if (outF32) {
        float* D = (float*)Dp + z * sliceD;
        #pragma unroll
        for (int r_ = 0; r_ < 4; ++r_) {
            float bv = bias ? bias[mrow + r_] : 0.f;
            #pragma unroll
            for (int nt = 0; nt < 16; ++nt)
                D[(size_t)(mrow + r_) * ldd + ncol + nt * 16] = acc[nt][r_] + bv;
        }
    } else {
        ushort* D = (ushort*)Dp + z * sliceD;
        #pragma unroll
        for (int r_ = 0; r_ < 4; ++r_) {
            float bv = bias ? bias[mrow + r_] : 0.f;
            #pragma unroll
            for (int nt = 0; nt < 16; ++nt)
                D[(size_t)(mrow + r_) * ldd + ncol + nt * 16] = f2bf(acc[nt][r_] + bv);
        }
    }
}

// ---- fused attention: per (m-tile 64, slice s) compute
//      S = Q Kt * temp (64x256), softmax rows, O = P @ Vt -> O[s][64][256]
__global__ __launch_bounds__(256) void attn_fused(const ushort* __restrict__ post,
                                                  const ushort* __restrict__ vt,
                                                  const float* __restrict__ temp,
                                                  ushort* __restrict__ O)
{
    __shared__ ushort Ws[64][40];     // Q tile [m][kchunk]
    __shared__ ushort Xs[256][40];    // K chunk then Vt chunk
    __shared__ ushort Ps[64][264];    // P (bf16) [m][y]
    int t = threadIdx.x, wv = t >> 6, lane = t & 63;
    int s = blockIdx.y;
    int b = s / 192, ch = s - b * 192;
    const ushort* Aq = post + ((size_t)b * 576 + ch) * HW;
    const ushort* Bk = Aq + (size_t)192 * HW;
    const ushort* Vt = vt + (size_t)s * HW;
    int m0 = blockIdx.x * 64;

    // ---- phase 1: S = Q K^T (contraction over w)
    f32x4 acc[16];
    #pragma unroll
    for (int i = 0; i < 16; ++i) acc[i] = (f32x4){0.f, 0.f, 0.f, 0.f};

    for (int k0 = 0; k0 < 256; k0 += 32) {
        {   int r = t >> 2, ss = t & 3;
            *(uint4*)&Ws[r][ss * 8] =
                *(const uint4*)(Aq + (size_t)(m0 + r) * IMW + k0 + ss * 8);
        }
        {   const ushort* bp = Bk + (size_t)t * IMW + k0;
            #pragma unroll
            for (int ss = 0; ss < 4; ++ss)
                *(uint4*)&Xs[t][ss * 8] = *(const uint4*)(bp + ss * 8);
        }
        __syncthreads();
        bf16x8 a = *(const bf16x8*)&Ws[wv * 16 + (lane & 15)][(lane >> 4) * 8];
        #pragma unroll
        for (int nt = 0; nt < 16; ++nt) {
            bf16x8 bfrag = *(const bf16x8*)&Xs[nt * 16 + (lane & 15)][(lane >> 4) * 8];
            acc[nt] = __builtin_amdgcn_mfma_f32_16x16x32_bf16(a, bfrag, acc[nt], 0, 0, 0);
        }
        __syncthreads();
    }

    // ---- phase 2: softmax rows (in-register, 16-lane groups), P -> LDS bf16
    float tv = temp[ch >> 5];
    #pragma unroll
    for (int r_ = 0; r_ < 4; ++r_) {
        float v[16];
        float mx = -3.4e38f;
        #pragma unroll
        for (int nt = 0; nt < 16; ++nt) { v[nt] = acc[nt][r_] * tv; mx = fmaxf(mx, v[nt]); }
        #pragma unroll
        for (int sh = 1; sh < 16; sh <<= 1) mx = fmaxf(mx, __shfl_xor(mx, sh, 64));
        float sum = 0.f;
        #pragma unroll
        for (int nt = 0; nt < 16; ++nt) { v[nt] = __expf(v[nt] - mx); sum += v[nt]; }
        #pragma unroll
        for (int sh = 1; sh < 16; sh <<= 1) sum += __shfl_xor(sum, sh, 64);
        float inv = 1.f / sum;
        int ml = wv * 16 + (lane >> 4) * 4 + r_;
        #pragma unroll
        for (int nt = 0; nt < 16; ++nt)
            Ps[ml][(lane & 15) + nt * 16] = f2bf(v[nt] * inv);
    }
    // each wave reads back only its own 16 rows of Ps -> no barrier needed for Ps;
    // Xs reuse is protected by the trailing barrier of phase 1 + the one below.

    // ---- phase 3: O = P @ Vt (contraction over y)
    f32x4 acc2[16];
    #pragma unroll
    for (int i = 0; i < 16; ++i) acc2[i] = (f32x4){0.f, 0.f, 0.f, 0.f};

    for (int y0 = 0; y0 < 256; y0 += 32) {
        {   const ushort* bp = Vt + (size_t)t * IMW + y0;
            #pragma unroll
            for (int ss = 0; ss < 4; ++ss)
                *(uint4*)&Xs[t][ss * 8] = *(const uint4*)(bp + ss * 8);
        }
        __syncthreads();
        bf16x8 a = *(const bf16x8*)&Ps[wv * 16 + (lane & 15)][y0 + (lane >> 4) * 8];
        #pragma unroll
        for (int nt = 0; nt < 16; ++nt) {
            bf16x8 bfrag = *(const bf16x8*)&Xs[nt * 16 + (lane & 15)][(lane >> 4) * 8];
            acc2[nt] = __builtin_amdgcn_mfma_f32_16x16x32_bf16(a, bfrag, acc2[nt], 0, 0, 0);
        }
        __syncthreads();
    }

    ushort* Op = O + (size_t)s * HW;
    int mrow = m0 + wv * 16 + (lane >> 4) * 4;
    int ncol = lane & 15;
    #pragma unroll
    for (int r_ = 0; r_ < 4; ++r_) {
        #pragma unroll
        for (int nt = 0; nt < 16; ++nt)
            Op[(size_t)(mrow + r_) * IMW + ncol + nt * 16] = f2bf(acc2[nt][r_]);
    }
}

// ---- depthwise 3x3 SAME + fused L2 row-norm (q,k), bf16, batched
__global__ __launch_bounds__(256) void dw3x3_l2norm(const ushort* __restrict__ in,
                                                    const float* __restrict__ w,
                                                    const float* __restrict__ bias,
                                                    ushort* __restrict__ out)
{
    int t = threadIdx.x;
    long gr = (long)blockIdx.x * 4 + (t >> 6);   // row over 4*576*256
    int lane = t & 63;
    int h  = (int)(gr & 255);
    long bc = gr >> 8;                            // b*576 + ch
    int ch = (int)(bc % 576);
    const ushort* img  = in  + (size_t)bc * HW;
    ushort*       outp = out + (size_t)bc * HW + (size_t)h * IMW;
    int px = lane * 4;

    const float* wch = w + ch * 9;
    float bv = bias[ch];
    float acc[4] = {bv, bv, bv, bv};
    #pragma unroll
    for (int dy = 0; dy < 3; ++dy) {
        int hh = h + dy - 1;
        if ((unsigned)hh > 255u) continue;
        const ushort* rowp = img + (size_t)hh * IMW;
        float v[6];
        ushort4 cv = *(const ushort4*)&rowp[px];
        v[1] = bf2f(cv.x); v[2] = bf2f(cv.y); v[3] = bf2f(cv.z); v[4] = bf2f(cv.w);
        v[0] = (px > 0)   ? bf2f(rowp[px - 1]) : 0.f;
        v[5] = (px < 252) ? bf2f(rowp[px + 4]) : 0.f;
        float w0 = wch[dy * 3], w1 = wch[dy * 3 + 1], w2 = wch[dy * 3 + 2];
        #pragma unroll
        for (int j = 0; j < 4; ++j)
            acc[j] += v[j] * w0 + v[j + 1] * w1 + v[j + 2] * w2;
    }
    if (ch < 384) {
        float ss = acc[0]*acc[0] + acc[1]*acc[1] + acc[2]*acc[2] + acc[3]*acc[3];
        #pragma unroll
        for (int m = 1; m < 64; m <<= 1) ss += __shfl_xor(ss, m, 64);
        float inv = 1.0f / fmaxf(sqrtf(ss), 1e-12f);
        acc[0] *= inv; acc[1] *= inv; acc[2] *= inv; acc[3] *= inv;
    }
    ushort4 o;
    o.x = f2bf(acc[0]); o.y = f2bf(acc[1]); o.z = f2bf(acc[2]); o.w = f2bf(acc[3]);
    *(ushort4*)&outp[px] = o;
}

extern "C" void kernel_launch(void* const* d_in, const int* in_sizes, int n_in,
                              void* d_out, int out_size, void* d_ws, size_t ws_size,
                              hipStream_t stream)
{
    const float* x      = (const float*)d_in[0];
    const float* qkv_w  = (const float*)d_in[1];
    const float* qkv_b  = (const float*)d_in[2];
    const float* dw_w   = (const float*)d_in[3];
    const float* dw_b   = (const float*)d_in[4];
    const float* proj_w = (const float*)d_in[5];
    const float* proj_b = (const float*)d_in[6];
    const float* temp   = (const float*)d_in[7];
    float* out = (float*)d_out;

    // ws layout (ushort elements)
    const size_t off_wq   = 0;                                // 110592
    const size_t off_wp   = 110592;                           // 36864
    const size_t off_pre  = 262144;                           // 4*576*HW
    const size_t off_post = off_pre + (size_t)4 * 576 * HW;   // 4*576*HW
    const size_t off_xt   = off_post + (size_t)4 * 576 * HW;  // 4*192*HW (Xt, later Vt)
    const size_t total_us = off_xt + (size_t)4 * 192 * HW;    // ~705 MB
    if (ws_size < total_us * sizeof(ushort)) return;

    ushort* wsb  = (ushort*)d_ws;
    ushort* wq   = wsb + off_wq;
    ushort* wp   = wsb + off_wp;
    ushort* pre  = wsb + off_pre;
    ushort* post = wsb + off_post;
    ushort* xt   = wsb + off_xt;                       // Xt then Vt
    ushort* Obuf = pre;                                // 4*192*HW (pre dead after dw)
    ushort* Otb  = pre + (size_t)4 * 192 * HW;         // 4*192*HW

    const long SL = (long)192 * HW;

    // weights -> bf16
    cvt_f32_bf16<<<dim3(432), 256, 0, stream>>>(qkv_w, wq, 110592);
    cvt_f32_bf16<<<dim3(144), 256, 0, stream>>>(proj_w, wp, 36864);

    // x [4][192][HW] fp32 -> Xt [4][HW][192] bf16
    cvt_transpose_f32<<<dim3(1024, 3, 4), 256, 0, stream>>>(x, xt, 192, HW, SL, SL);
    // qkv = Wq @ x : pre [4][576][HW] bf16
    gemm_mfma<<<dim3(9, 256, 4), 256, 0, stream>>>(wq, 192, 0, xt, 192, SL,
                                                   pre, HW, (long)576 * HW, qkv_b, 192, 0);
    // depthwise 3x3 + l2norm(q,k): post [4][576][HW]
    dw3x3_l2norm<<<dim3(147456), 256, 0, stream>>>(pre, dw_w, dw_b, post);
    // V -> Vt (into xt region; Xt dead)
    transpose_v<<<dim3(4, 4, 768), 256, 0, stream>>>(post, xt);
    // fused attention -> O [4][192][HW] bf16 (reuses pre)
    attn_fused<<<dim3(4, 768), 256, 0, stream>>>(post, xt, temp, Obuf);
    // O -> Ot [4][HW][192]
    transpose_bf16<<<dim3(1024, 3, 4), 256, 0, stream>>>(Obuf, Otb, 192, HW, SL, SL);
    // out = Wp @ O + b : fp32
    gemm_mfma<<<dim3(3, 256, 4), 256, 0, stream>>>(wp, 192, 0, Otb, 192, SL,
                                                   out, HW, SL, proj_b, 192, 1);
}

// Round 6
// 800.889 us; speedup vs baseline: 2.6028x; 1.3580x over previous
//
#include <hip/hip_runtime.h>
#include <hip/hip_bf16.h>
#include <math.h>

// ============================================================================
// XCA transposed attention, bf16-MFMA, round 5: fast dwconv (shuffle halo,
// register row-staging, 4 rows/wave). Rest unchanged from round 4.
// ============================================================================

#define HW 65536
#define IMW 256

typedef short bf16x8 __attribute__((ext_vector_type(8)));
typedef float f32x4  __attribute__((ext_vector_type(4)));

__device__ __forceinline__ float bf2f(ushort u) {
    return __uint_as_float((uint)u << 16);
}
__device__ __forceinline__ ushort f2bf(float f) {
    uint i = __float_as_uint(f);
    return (ushort)((i + 0x7FFFu + ((i >> 16) & 1u)) >> 16);
}

// ---- flat fp32 -> bf16 (weights)
__global__ __launch_bounds__(256) void cvt_f32_bf16(const float* __restrict__ s,
                                                    ushort* __restrict__ d, int n)
{
    int i = blockIdx.x * 256 + threadIdx.x;
    if (i < n) d[i] = f2bf(s[i]);
}

// ---- fp32 [R][C] -> bf16 [C][R] transpose+convert, 64x64 tiles, z-sliced
__global__ __launch_bounds__(256) void cvt_transpose_f32(const float* __restrict__ src,
                                                         ushort* __restrict__ dst,
                                                         int R, int C,
                                                         long ssS, long ssD)
{
    __shared__ ushort Ls[64][72];
    int t = threadIdx.x;
    long z = blockIdx.z;
    src += z * ssS; dst += z * ssD;
    int c0 = blockIdx.x * 64, r0 = blockIdx.y * 64;
    {
        int r = t >> 2, cs = t & 3;
        const float* gp = src + (size_t)(r0 + r) * C + c0 + cs * 16;
        ushort tmp[16];
        #pragma unroll
        for (int q = 0; q < 4; ++q) {
            float4 v = *(const float4*)(gp + q * 4);
            tmp[q*4+0] = f2bf(v.x); tmp[q*4+1] = f2bf(v.y);
            tmp[q*4+2] = f2bf(v.z); tmp[q*4+3] = f2bf(v.w);
        }
        *(uint4*)&Ls[r][cs * 16]     = *(uint4*)&tmp[0];
        *(uint4*)&Ls[r][cs * 16 + 8] = *(uint4*)&tmp[8];
    }
    __syncthreads();
    {
        int cc = t & 63, seg = t >> 6;
        ushort tmp[16];
        #pragma unroll
        for (int j = 0; j < 16; ++j) tmp[j] = Ls[seg * 16 + j][cc];
        ushort* op = dst + (size_t)(c0 + cc) * R + r0 + seg * 16;
        *(uint4*)(op)     = *(uint4*)&tmp[0];
        *(uint4*)(op + 8) = *(uint4*)&tmp[8];
    }
}

// ---- bf16 [R][C] -> bf16 [C][R] transpose, 64x64 tiles, z-sliced
__global__ __launch_bounds__(256) void transpose_bf16(const ushort* __restrict__ src,
                                                      ushort* __restrict__ dst,
                                                      int R, int C,
                                                      long ssS, long ssD)
{
    __shared__ ushort Ls[64][72];
    int t = threadIdx.x;
    long z = blockIdx.z;
    src += z * ssS; dst += z * ssD;
    int c0 = blockIdx.x * 64, r0 = blockIdx.y * 64;
    {
        int r = t >> 2, cs = t & 3;
        const ushort* gp = src + (size_t)(r0 + r) * C + c0 + cs * 16;
        *(uint4*)&Ls[r][cs * 16]     = *(const uint4*)(gp);
        *(uint4*)&Ls[r][cs * 16 + 8] = *(const uint4*)(gp + 8);
    }
    __syncthreads();
    {
        int cc = t & 63, seg = t >> 6;
        ushort tmp[16];
        #pragma unroll
        for (int j = 0; j < 16; ++j) tmp[j] = Ls[seg * 16 + j][cc];
        ushort* op = dst + (size_t)(c0 + cc) * R + r0 + seg * 16;
        *(uint4*)(op)     = *(uint4*)&tmp[0];
        *(uint4*)(op + 8) = *(uint4*)&tmp[8];
    }
}

// ---- V [b][384+r][256][256] -> Vt [s=b*192+r][256][256]^T
__global__ __launch_bounds__(256) void transpose_v(const ushort* __restrict__ post,
                                                   ushort* __restrict__ vt)
{
    __shared__ ushort Ls[64][72];
    int t = threadIdx.x;
    int s = blockIdx.z;
    int b = s / 192, r = s - b * 192;
    const ushort* src = post + ((size_t)b * 576 + 384 + r) * HW;
    ushort*       dst = vt + (size_t)s * HW;
    int c0 = blockIdx.x * 64, r0 = blockIdx.y * 64;
    {
        int rr = t >> 2, cs = t & 3;
        const ushort* gp = src + (size_t)(r0 + rr) * IMW + c0 + cs * 16;
        *(uint4*)&Ls[rr][cs * 16]     = *(const uint4*)(gp);
        *(uint4*)&Ls[rr][cs * 16 + 8] = *(const uint4*)(gp + 8);
    }
    __syncthreads();
    {
        int cc = t & 63, seg = t >> 6;
        ushort tmp[16];
        #pragma unroll
        for (int j = 0; j < 16; ++j) tmp[j] = Ls[seg * 16 + j][cc];
        ushort* op = dst + (size_t)(c0 + cc) * IMW + r0 + seg * 16;
        *(uint4*)(op)     = *(uint4*)&tmp[0];
        *(uint4*)(op + 8) = *(uint4*)&tmp[8];
    }
}

// ---- generic MFMA GEMM: D[m][n] = sum_k A[m][k]*B[n][k] (+bias[m])
__global__ __launch_bounds__(256) void gemm_mfma(const ushort* __restrict__ A, int lda, long sliceA,
                                                 const ushort* __restrict__ B, int ldb, long sliceB,
                                                 void* __restrict__ Dp, int ldd, long sliceD,
                                                 const float* __restrict__ bias,
                                                 int K, int outF32)
{
    __shared__ ushort Ws[64][40];
    __shared__ ushort Xs[256][40];
    int t = threadIdx.x, wv = t >> 6, lane = t & 63;
    long z = blockIdx.z;
    A += z * sliceA; B += z * sliceB;
    int m0 = blockIdx.x * 64, n0 = blockIdx.y * 256;

    f32x4 acc[16];
    #pragma unroll
    for (int i = 0; i < 16; ++i) acc[i] = (f32x4){0.f, 0.f, 0.f, 0.f};

    for (int k0 = 0; k0 < K; k0 += 32) {
        {   int r = t >> 2, s = t & 3;
            *(uint4*)&Ws[r][s * 8] =
                *(const uint4*)(A + (size_t)(m0 + r) * lda + k0 + s * 8);
        }
        {   const ushort* bp = B + (size_t)(n0 + t) * ldb + k0;
            #pragma unroll
            for (int s = 0; s < 4; ++s)
                *(uint4*)&Xs[t][s * 8] = *(const uint4*)(bp + s * 8);
        }
        __syncthreads();
        bf16x8 a = *(const bf16x8*)&Ws[wv * 16 + (lane & 15)][(lane >> 4) * 8];
        #pragma unroll
        for (int nt = 0; nt < 16; ++nt) {
            bf16x8 b = *(const bf16x8*)&Xs[nt * 16 + (lane & 15)][(lane >> 4) * 8];
            acc[nt] = __builtin_amdgcn_mfma_f32_16x16x32_bf16(a, b, acc[nt], 0, 0, 0);
        }
        __syncthreads();
    }

    int mrow = m0 + wv * 16 + (lane >> 4) * 4;
    int ncol = n0 + (lane & 15);
    if (outF32) {
        float* D = (float*)Dp + z * sliceD;
        #pragma unroll
        for (int r_ = 0; r_ < 4; ++r_) {
            float bv = bias ? bias[mrow + r_] : 0.f;
            #pragma unroll
            for (int nt = 0; nt < 16; ++nt)
                D[(size_t)(mrow + r_) * ldd + ncol + nt * 16] = acc[nt][r_] + bv;
        }
    } else {
        ushort* D = (ushort*)Dp + z * sliceD;
        #pragma unroll
        for (int r_ = 0; r_ < 4; ++r_) {
            float bv = bias ? bias[mrow + r_] : 0.f;
            #pragma unroll
            for (int nt = 0; nt < 16; ++nt)
                D[(size_t)(mrow + r_) * ldd + ncol + nt * 16] = f2bf(acc[nt][r_] + bv);
        }
    }
}

// ---- fused attention: per (m-tile 64, slice s): S=QK^T*t, softmax, O=P@Vt
__global__ __launch_bounds__(256) void attn_fused(const ushort* __restrict__ post,
                                                  const ushort* __restrict__ vt,
                                                  const float* __restrict__ temp,
                                                  ushort* __restrict__ O)
{
    __shared__ ushort Ws[64][40];
    __shared__ ushort Xs[256][40];
    __shared__ ushort Ps[64][264];
    int t = threadIdx.x, wv = t >> 6, lane = t & 63;
    int s = blockIdx.y;
    int b = s / 192, ch = s - b * 192;
    const ushort* Aq = post + ((size_t)b * 576 + ch) * HW;
    const ushort* Bk = Aq + (size_t)192 * HW;
    const ushort* Vt = vt + (size_t)s * HW;
    int m0 = blockIdx.x * 64;

    f32x4 acc[16];
    #pragma unroll
    for (int i = 0; i < 16; ++i) acc[i] = (f32x4){0.f, 0.f, 0.f, 0.f};

    for (int k0 = 0; k0 < 256; k0 += 32) {
        {   int r = t >> 2, ss = t & 3;
            *(uint4*)&Ws[r][ss * 8] =
                *(const uint4*)(Aq + (size_t)(m0 + r) * IMW + k0 + ss * 8);
        }
        {   const ushort* bp = Bk + (size_t)t * IMW + k0;
            #pragma unroll
            for (int ss = 0; ss < 4; ++ss)
                *(uint4*)&Xs[t][ss * 8] = *(const uint4*)(bp + ss * 8);
        }
        __syncthreads();
        bf16x8 a = *(const bf16x8*)&Ws[wv * 16 + (lane & 15)][(lane >> 4) * 8];
        #pragma unroll
        for (int nt = 0; nt < 16; ++nt) {
            bf16x8 bfrag = *(const bf16x8*)&Xs[nt * 16 + (lane & 15)][(lane >> 4) * 8];
            acc[nt] = __builtin_amdgcn_mfma_f32_16x16x32_bf16(a, bfrag, acc[nt], 0, 0, 0);
        }
        __syncthreads();
    }

    float tv = temp[ch >> 5];
    #pragma unroll
    for (int r_ = 0; r_ < 4; ++r_) {
        float v[16];
        float mx = -3.4e38f;
        #pragma unroll
        for (int nt = 0; nt < 16; ++nt) { v[nt] = acc[nt][r_] * tv; mx = fmaxf(mx, v[nt]); }
        #pragma unroll
        for (int sh = 1; sh < 16; sh <<= 1) mx = fmaxf(mx, __shfl_xor(mx, sh, 64));
        float sum = 0.f;
        #pragma unroll
        for (int nt = 0; nt < 16; ++nt) { v[nt] = __expf(v[nt] - mx); sum += v[nt]; }
        #pragma unroll
        for (int sh = 1; sh < 16; sh <<= 1) sum += __shfl_xor(sum, sh, 64);
        float inv = 1.f / sum;
        int ml = wv * 16 + (lane >> 4) * 4 + r_;
        #pragma unroll
        for (int nt = 0; nt < 16; ++nt)
            Ps[ml][(lane & 15) + nt * 16] = f2bf(v[nt] * inv);
    }

    f32x4 acc2[16];
    #pragma unroll
    for (int i = 0; i < 16; ++i) acc2[i] = (f32x4){0.f, 0.f, 0.f, 0.f};

    for (int y0 = 0; y0 < 256; y0 += 32) {
        {   const ushort* bp = Vt + (size_t)t * IMW + y0;
            #pragma unroll
            for (int ss = 0; ss < 4; ++ss)
                *(uint4*)&Xs[t][ss * 8] = *(const uint4*)(bp + ss * 8);
        }
        __syncthreads();
        bf16x8 a = *(const bf16x8*)&Ps[wv * 16 + (lane & 15)][y0 + (lane >> 4) * 8];
        #pragma unroll
        for (int nt = 0; nt < 16; ++nt) {
            bf16x8 bfrag = *(const bf16x8*)&Xs[nt * 16 + (lane & 15)][(lane >> 4) * 8];
            acc2[nt] = __builtin_amdgcn_mfma_f32_16x16x32_bf16(a, bfrag, acc2[nt], 0, 0, 0);
        }
        __syncthreads();
    }

    ushort* Op = O + (size_t)s * HW;
    int mrow = m0 + wv * 16 + (lane >> 4) * 4;
    int ncol = lane & 15;
    #pragma unroll
    for (int r_ = 0; r_ < 4; ++r_) {
        #pragma unroll
        for (int nt = 0; nt < 16; ++nt)
            Op[(size_t)(mrow + r_) * IMW + ncol + nt * 16] = f2bf(acc2[nt][r_]);
    }
}

// ---- depthwise 3x3 SAME + fused L2 row-norm, register-staged, shuffle halo.
// wave = 4 output rows of one channel; block = 4 waves = 16 rows.
// grid (16, 576, 4): blockIdx.x=row-group, y=channel, z=batch.
__global__ __launch_bounds__(256) void dw3x3_l2norm(const ushort* __restrict__ in,
                                                    const float* __restrict__ w,
                                                    const float* __restrict__ bias,
                                                    ushort* __restrict__ out)
{
    int t = threadIdx.x;
    int lane = t & 63, wv = t >> 6;
    int ch = blockIdx.y;
    int r0 = blockIdx.x * 16 + wv * 4;
    const ushort* img  = in  + ((size_t)blockIdx.z * 576 + ch) * HW;
    ushort*       outp = out + ((size_t)blockIdx.z * 576 + ch) * HW;
    int px = lane * 4;

    // stage rows r0-1 .. r0+4 (zeros outside image)
    float rv[6][4], lv[6], rx[6];
    #pragma unroll
    for (int i = 0; i < 6; ++i) {
        int rr = r0 - 1 + i;
        if ((unsigned)rr <= 255u) {
            ushort4 cv = *(const ushort4*)&img[(size_t)rr * IMW + px];
            rv[i][0] = bf2f(cv.x); rv[i][1] = bf2f(cv.y);
            rv[i][2] = bf2f(cv.z); rv[i][3] = bf2f(cv.w);
        } else {
            rv[i][0] = rv[i][1] = rv[i][2] = rv[i][3] = 0.f;
        }
        float l = __shfl_up(rv[i][3], 1, 64);
        lv[i] = (lane == 0) ? 0.f : l;
        float r = __shfl_down(rv[i][0], 1, 64);
        rx[i] = (lane == 63) ? 0.f : r;
    }

    const float* wch = w + ch * 9;
    float bv = bias[ch];
    bool do_norm = (ch < 384);

    #pragma unroll
    for (int j = 0; j < 4; ++j) {
        float a0 = bv, a1 = bv, a2 = bv, a3 = bv;
        #pragma unroll
        for (int dy = 0; dy < 3; ++dy) {
            int i = j + dy;
            float w0 = wch[dy * 3], w1 = wch[dy * 3 + 1], w2 = wch[dy * 3 + 2];
            a0 += lv[i]    * w0 + rv[i][0] * w1 + rv[i][1] * w2;
            a1 += rv[i][0] * w0 + rv[i][1] * w1 + rv[i][2] * w2;
            a2 += rv[i][1] * w0 + rv[i][2] * w1 + rv[i][3] * w2;
            a3 += rv[i][2] * w0 + rv[i][3] * w1 + rx[i]    * w2;
        }
        if (do_norm) {
            float ss = a0 * a0 + a1 * a1 + a2 * a2 + a3 * a3;
            #pragma unroll
            for (int m = 1; m < 64; m <<= 1) ss += __shfl_xor(ss, m, 64);
            float inv = 1.0f / fmaxf(sqrtf(ss), 1e-12f);
            a0 *= inv; a1 *= inv; a2 *= inv; a3 *= inv;
        }
        ushort4 o;
        o.x = f2bf(a0); o.y = f2bf(a1); o.z = f2bf(a2); o.w = f2bf(a3);
        *(ushort4*)&outp[(size_t)(r0 + j) * IMW + px] = o;
    }
}

extern "C" void kernel_launch(void* const* d_in, const int* in_sizes, int n_in,
                              void* d_out, int out_size, void* d_ws, size_t ws_size,
                              hipStream_t stream)
{
    const float* x      = (const float*)d_in[0];
    const float* qkv_w  = (const float*)d_in[1];
    const float* qkv_b  = (const float*)d_in[2];
    const float* dw_w   = (const float*)d_in[3];
    const float* dw_b   = (const float*)d_in[4];
    const float* proj_w = (const float*)d_in[5];
    const float* proj_b = (const float*)d_in[6];
    const float* temp   = (const float*)d_in[7];
    float* out = (float*)d_out;

    // ws layout (ushort elements)
    const size_t off_wq   = 0;                                // 110592
    const size_t off_wp   = 110592;                           // 36864
    const size_t off_pre  = 262144;                           // 4*576*HW
    const size_t off_post = off_pre + (size_t)4 * 576 * HW;   // 4*576*HW
    const size_t off_xt   = off_post + (size_t)4 * 576 * HW;  // 4*192*HW (Xt, later Vt)
    const size_t total_us = off_xt + (size_t)4 * 192 * HW;    // ~705 MB
    if (ws_size < total_us * sizeof(ushort)) return;

    ushort* wsb  = (ushort*)d_ws;
    ushort* wq   = wsb + off_wq;
    ushort* wp   = wsb + off_wp;
    ushort* pre  = wsb + off_pre;
    ushort* post = wsb + off_post;
    ushort* xt   = wsb + off_xt;                       // Xt then Vt
    ushort* Obuf = pre;                                // 4*192*HW (pre dead after dw)
    ushort* Otb  = pre + (size_t)4 * 192 * HW;         // 4*192*HW

    const long SL = (long)192 * HW;

    cvt_f32_bf16<<<dim3(432), 256, 0, stream>>>(qkv_w, wq, 110592);
    cvt_f32_bf16<<<dim3(144), 256, 0, stream>>>(proj_w, wp, 36864);

    cvt_transpose_f32<<<dim3(1024, 3, 4), 256, 0, stream>>>(x, xt, 192, HW, SL, SL);
    gemm_mfma<<<dim3(9, 256, 4), 256, 0, stream>>>(wq, 192, 0, xt, 192, SL,
                                                   pre, HW, (long)576 * HW, qkv_b, 192, 0);
    dw3x3_l2norm<<<dim3(16, 576, 4), 256, 0, stream>>>(pre, dw_w, dw_b, post);
    transpose_v<<<dim3(4, 4, 768), 256, 0, stream>>>(post, xt);
    attn_fused<<<dim3(4, 768), 256, 0, stream>>>(post, xt, temp, Obuf);
    transpose_bf16<<<dim3(1024, 3, 4), 256, 0, stream>>>(Obuf, Otb, 192, HW, SL, SL);
    gemm_mfma<<<dim3(3, 256, 4), 256, 0, stream>>>(wp, 192, 0, Otb, 192, SL,
                                                   out, HW, SL, proj_b, 192, 1);
}